// Round 5
// baseline (127.486 us; speedup 1.0000x reference)
//
#include <hip/hip_runtime.h>

typedef __bf16 bf16;
typedef __attribute__((ext_vector_type(4))) bf16 bf16x4;
typedef __attribute__((ext_vector_type(8))) bf16 bf16x8;
typedef __attribute__((ext_vector_type(4))) float f32x4;

namespace {

// ---- compile-time physical constants (double) ----
constexpr double csqrt(double x) {
  double s = x > 1 ? x : 1;
  for (int i = 0; i < 60; ++i) s = 0.5 * (s + x / s);
  return s;
}
constexpr double AP_D =
    ((3.667 - 1.0) / (3.667 + 0.5)) * (0.3 * (7.5 * csqrt(7.5)) / 0.0002395);
constexpr double RGAST_D = (8.3144598 / 4184.0) * 623.15;

__device__ __forceinline__ float sss_val(int i, int j) {
  // SSS[i][j] = exp(-DELTAW/(RGAS*T)); symmetric; zero outside 51x51 (pad)
  if (i > 50 || j > 50) return 0.0f;
  const float si = -0.025f + 0.001f * (float)i;
  const float sj = -0.025f + 0.001f * (float)j;
  const float acc = fmaxf(0.0f, fmaxf(si, sj) - 0.0084f);
  const float don = fminf(0.0f, fminf(si, sj) + 0.0084f);
  const float dw = (float)(AP_D * 0.5) * (si + sj) * (si + sj) + 85580.0f * acc * don;
  return expf(-dw * (float)(1.0 / RGAST_D));
}

__device__ __forceinline__ float fast_log(float x) {
  return __builtin_amdgcn_logf(x) * 0.69314718056f;   // ln via log2
}

__device__ __forceinline__ f32x4 mfma16(bf16x8 a, bf16x8 b, f32x4 c) {
  return __builtin_amdgcn_mfma_f32_16x16x32_bf16(a, b, c, 0, 0, 0);
}

} // namespace

// One wave = 16 solves (8 elements x {pure, mix}) -> 4096 waves = 4/SIMD
// (R4's 32-solve waves gave only 2/SIMD: latency-bound at 1490 cyc/iter).
// Per iteration: D[n_out, s] = Sigma_k S[n_out,k] * H[k,s] via 4 m-tiles x
// 2 k-tiles of v_mfma_f32_16x16x32_bf16 (A = S const frags; B = H via LDS).
// C/D layout: col = lane&15 = solve s, row = 16t + 4*(lane>>4) + reg.
// A layout:   A[m = lane&15][k = 8*(lane>>4) + i], K-tile offset 32kt.
// LDS slab per wave: [s][k] bf16, stride 72 (16B-aligned b128 reads).
// Pads: S rows/cols >=51 are 0; invalid rows get d += 1 -> G stays 1 (ln=0);
// w = 0 on pad n keeps H = 0. Wave-private LDS -> no barriers.
__global__ __launch_bounds__(256, 4) void cosmo_mfma16(
    const float* __restrict__ my_sigma,   // [B,51]
    const float* __restrict__ v_comp,     // [B]
    const float* __restrict__ vt_sigma,   // [B,51,2]
    const float* __restrict__ v_vt,       // [B]
    float* __restrict__ out,              // [B]
    int B)
{
  __shared__ bf16 lds[4][16 * 72];

  const int lane = threadIdx.x & 63;
  const int wv   = threadIdx.x >> 6;
  const int s    = lane & 15;     // solve slot
  const int g    = lane >> 4;     // lane group 0..3
  const int e    = blockIdx.x * 32 + wv * 8 + (s >> 1);
  const int task = s & 1;         // 0 = pure, 1 = mix
  const bool ein = (e < B);
  const int  ec  = ein ? e : 0;

  // ---- rows owned by this lane: n = 16t + 4g + r ----
  float myv[16], vtv[16];
#pragma unroll
  for (int t = 0; t < 4; ++t)
#pragma unroll
    for (int r = 0; r < 4; ++r) {
      const int n  = 16 * t + 4 * g + r;
      const bool nv = (n < 51) && ein;
      const int nc = (n < 51) ? n : 50;
      myv[4 * t + r] = nv ? my_sigma[(size_t)ec * 51 + nc] : 0.0f;
      vtv[4 * t + r] = nv ? vt_sigma[((size_t)ec * 51 + nc) * 2 + 1] : 0.0f;
    }

  float pA0 = 0.f, pA1 = 0.f;
#pragma unroll
  for (int i = 0; i < 16; ++i) { pA0 += myv[i]; pA1 += vtv[i]; }
  float A0 = pA0; A0 += __shfl_xor(A0, 16, 64); A0 += __shfl_xor(A0, 32, 64);
  float A1 = pA1; A1 += __shfl_xor(A1, 16, 64); A1 += __shfl_xor(A1, 32, 64);

  const float den  = task ? (0.235f * A0 + 0.765f * A1) : A0;
  const float rden = __builtin_amdgcn_rcpf(den);
  const float rA0  = __builtin_amdgcn_rcpf(A0);

  float wC[16], G[16];
#pragma unroll
  for (int i = 0; i < 16; ++i) {
    const float num = task ? (0.235f * myv[i] + 0.765f * vtv[i]) : myv[i];
    wC[i] = num * rden;     // psigma of this task; 0 on pads
    G[i]  = 1.0f;
  }

  // ---- constant A fragments: afr[t][kt][i] = S[16t+s][32kt + 8g + i] ----
  bf16x8 afr[4][2];
#pragma unroll
  for (int t = 0; t < 4; ++t)
#pragma unroll
    for (int kt = 0; kt < 2; ++kt) {
      bf16x8 v;
#pragma unroll
      for (int i = 0; i < 8; ++i)
        v[i] = (bf16)sss_val(16 * t + s, 32 * kt + 8 * g + i);
      afr[t][kt] = v;
    }

  bf16* slab = &lds[wv][0];
  const int wb = s * 72 + 4 * g;   // + 16t : b64 writes (8B aligned)
  const int rb = s * 72 + 8 * g;   // + 32kt: b128 reads (16B aligned)
  const float gpad = (g == 0) ? 0.0f : 1.0f;   // tile-3 row validity

  // ---- 50-step damped fixed point: G <- 0.5*(G + 1/(S @ (w*G))) ----
#pragma unroll 1
  for (int it = 0; it < 50; ++it) {
#pragma unroll
    for (int t = 0; t < 4; ++t) {
      bf16x4 hv;
#pragma unroll
      for (int r = 0; r < 4; ++r)
        hv[r] = (bf16)(wC[4 * t + r] * G[4 * t + r]);
      *(bf16x4*)(slab + wb + 16 * t) = hv;
    }

    const bf16x8 bfr0 = *(const bf16x8*)(slab + rb);
    const bf16x8 bfr1 = *(const bf16x8*)(slab + rb + 32);

    const f32x4 z = {};
    f32x4 acc[4];
#pragma unroll
    for (int t = 0; t < 4; ++t) acc[t] = mfma16(afr[t][0], bfr0, z);
#pragma unroll
    for (int t = 0; t < 4; ++t) acc[t] = mfma16(afr[t][1], bfr1, acc[t]);

#pragma unroll
    for (int t = 0; t < 3; ++t)
#pragma unroll
      for (int r = 0; r < 4; ++r)
        G[4 * t + r] = 0.5f * (G[4 * t + r] + __builtin_amdgcn_rcpf(acc[t][r]));
#pragma unroll
    for (int r = 0; r < 4; ++r) {          // tile 3: n = 48 + 4g + r
      const float d = acc[3][r] + ((r < 3) ? gpad : 1.0f);
      G[12 + r] = 0.5f * (G[12 + r] + __builtin_amdgcn_rcpf(d));
    }
  }

  // ---- epilogue: S_task = sum_n psigma_pure[n] * ln(G[n]) ----
  float Sp = 0.f;
#pragma unroll
  for (int t = 0; t < 4; ++t)
#pragma unroll
    for (int r = 0; r < 4; ++r) {
      const int n = 16 * t + 4 * g + r;
      if (n < 51) {
        const float p = (ein ? my_sigma[(size_t)ec * 51 + n] : 0.0f) * rA0;
        Sp += p * __builtin_amdgcn_logf(G[4 * t + r]);
      }
    }
  Sp += __shfl_xor(Sp, 16, 64);
  Sp += __shfl_xor(Sp, 32, 64);
  const float St = Sp * 0.69314718056f;
  const float So = __shfl_xor(St, 1, 64);   // partner task's sum

  if (task == 0 && g == 0 && ein) {
    const float lng_resid = A0 * (1.0f / 7.5f) * (So - St);
    const float v0  = v_comp[e];
    const float v1v = v_vt[e];
    const float q0 = A0 * (1.0f / 79.53f), q1 = A1 * (1.0f / 79.53f);
    const float r0 = v0 * (1.0f / 66.69f), r1 = v1v * (1.0f / 66.69f);
    const float xq = 0.235f * q0 + 0.765f * q1;
    const float xr = 0.235f * r0 + 0.765f * r1;
    const float theta = 0.235f * q0 * __builtin_amdgcn_rcpf(xq);
    const float phi   = 0.235f * r0 * __builtin_amdgcn_rcpf(xr);
    const float l0 = 5.0f * (r0 - q0) - (r0 - 1.0f);
    const float l1 = 5.0f * (r1 - q1) - (r1 - 1.0f);
    const float xl = 0.235f * l0 + 0.765f * l1;
    const float lng_comb = fast_log(phi * (1.0f / 0.235f))
                         + 5.0f * q0 * fast_log(theta * __builtin_amdgcn_rcpf(phi))
                         + l0 - (phi * (1.0f / 0.235f)) * xl;
    out[e] = lng_resid + lng_comb;
  }
}

extern "C" void kernel_launch(void* const* d_in, const int* in_sizes, int n_in,
                              void* d_out, int out_size, void* d_ws, size_t ws_size,
                              hipStream_t stream) {
  const float* my  = (const float*)d_in[0];
  const float* vc  = (const float*)d_in[1];
  const float* vts = (const float*)d_in[2];
  const float* vvt = (const float*)d_in[3];
  float* out = (float*)d_out;
  const int B = in_sizes[1];                    // v_compound is [B]
  const int grid = (B + 31) / 32;               // 32 elements per 256-thread block
  cosmo_mfma16<<<grid, 256, 0, stream>>>(my, vc, vts, vvt, out, B);
}

// Round 8
// 122.611 us; speedup vs baseline: 1.0398x; 1.0398x over previous
//
#include <hip/hip_runtime.h>

typedef __bf16 bf16;
typedef __attribute__((ext_vector_type(4))) bf16 bf16x4;
typedef __attribute__((ext_vector_type(8))) bf16 bf16x8;
typedef __attribute__((ext_vector_type(4))) float f32x4;

namespace {

// ---- compile-time physical constants (double) ----
constexpr double csqrt(double x) {
  double s = x > 1 ? x : 1;
  for (int i = 0; i < 60; ++i) s = 0.5 * (s + x / s);
  return s;
}
constexpr double AP_D =
    ((3.667 - 1.0) / (3.667 + 0.5)) * (0.3 * (7.5 * csqrt(7.5)) / 0.0002395);
constexpr double RGAST_D = (8.3144598 / 4184.0) * 623.15;

__device__ __forceinline__ float sss_val(int i, int j) {
  // SSS[i][j] = exp(-DELTAW/(RGAS*T)); symmetric; zero outside 51x51 (pad)
  if (i > 50 || j > 50) return 0.0f;
  const float si = -0.025f + 0.001f * (float)i;
  const float sj = -0.025f + 0.001f * (float)j;
  const float acc = fmaxf(0.0f, fmaxf(si, sj) - 0.0084f);
  const float don = fminf(0.0f, fminf(si, sj) + 0.0084f);
  const float dw = (float)(AP_D * 0.5) * (si + sj) * (si + sj) + 85580.0f * acc * don;
  return expf(-dw * (float)(1.0 / RGAST_D));
}

__device__ __forceinline__ float fast_log(float x) {
  return __builtin_amdgcn_logf(x) * 0.69314718056f;   // ln via log2
}

// HW-verified gfx950 shape (guide §3 list; R4/R5 passed with it).
__device__ __forceinline__ f32x4 mfma16(bf16x8 a, bf16x8 b, f32x4 c) {
  return __builtin_amdgcn_mfma_f32_16x16x32_bf16(a, b, c, 0, 0, 0);
}

} // namespace

// One wave per block = 16 solves (8 elements x {pure, mix}); 4096 blocks ->
// 16 waves/CU (R5's 4-wave blocks balanced poorly: 2.36 waves/SIMD avg).
// State is Gt = w (.) G  -> the MFMA B operand is cvt(Gt) directly (no H mul).
// Update: Gt' = 0.5*(Gt + w * rcp(d)). Same fixed point, fewer VALU ops.
// Per iteration: D[n_out, s] = Sigma_k S[n_out,k] * Gt_bf16[k,s] via 4 m-tiles
// x 2 k-tiles of v_mfma_f32_16x16x32_bf16 (A = S const frags; B via LDS).
// LDS [s][k] bf16 stride 68 (136 B -> bank step 2 -> free 2-way only; R5's
// stride 72 cost 4.9M conflict cycles). b64 reads (8B-aligned) not b128.
// Pads: S rows/cols >=51 are 0; pad out-rows get d+=1, w=0 -> Gt stays 0.
__global__ __launch_bounds__(64, 4) void cosmo_mfma_gt(
    const float* __restrict__ my_sigma,   // [B,51]
    const float* __restrict__ v_comp,     // [B]
    const float* __restrict__ vt_sigma,   // [B,51,2]
    const float* __restrict__ v_vt,       // [B]
    float* __restrict__ out,              // [B]
    int B)
{
  __shared__ bf16 lds[16 * 68];

  const int lane = threadIdx.x;   // block == one wave
  const int s    = lane & 15;     // solve slot
  const int g    = lane >> 4;     // lane group 0..3
  const int e    = blockIdx.x * 8 + (s >> 1);
  const int task = s & 1;         // 0 = pure, 1 = mix
  const bool ein = (e < B);
  const int  ec  = ein ? e : 0;

  // ---- rows owned by this lane in C layout: n = 16t + 4g + r ----
  float A0, A1, wC[16];
  {
    float myv[16], vtv[16];
#pragma unroll
    for (int t = 0; t < 4; ++t)
#pragma unroll
      for (int r = 0; r < 4; ++r) {
        const int n  = 16 * t + 4 * g + r;
        const bool nv = (n < 51) && ein;
        const int nc = (n < 51) ? n : 50;
        myv[4 * t + r] = nv ? my_sigma[(size_t)ec * 51 + nc] : 0.0f;
        vtv[4 * t + r] = nv ? vt_sigma[((size_t)ec * 51 + nc) * 2 + 1] : 0.0f;
      }
    float pA0 = 0.f, pA1 = 0.f;
#pragma unroll
    for (int i = 0; i < 16; ++i) { pA0 += myv[i]; pA1 += vtv[i]; }
    A0 = pA0; A0 += __shfl_xor(A0, 16, 64); A0 += __shfl_xor(A0, 32, 64);
    A1 = pA1; A1 += __shfl_xor(A1, 16, 64); A1 += __shfl_xor(A1, 32, 64);

    const float den  = task ? (0.235f * A0 + 0.765f * A1) : A0;
    const float rden = __builtin_amdgcn_rcpf(den);
#pragma unroll
    for (int i = 0; i < 16; ++i) {
      const float num = task ? (0.235f * myv[i] + 0.765f * vtv[i]) : myv[i];
      wC[i] = num * rden;     // psigma of this task; 0 on pads
    }
  }

  float Gt[16];                   // state: Gt = w * G, init G = 1
#pragma unroll
  for (int i = 0; i < 16; ++i) Gt[i] = wC[i];

  // ---- constant A fragments: afr[t][kt][i] = S[16t+s][32kt + 8g + i] ----
  bf16x8 afr[4][2];
#pragma unroll
  for (int t = 0; t < 4; ++t)
#pragma unroll
    for (int kt = 0; kt < 2; ++kt) {
      bf16x8 v;
#pragma unroll
      for (int i = 0; i < 8; ++i)
        v[i] = (bf16)sss_val(16 * t + s, 32 * kt + 8 * g + i);
      afr[t][kt] = v;
    }

  const int wb = s * 68 + 4 * g;   // + 16t : b64 writes (8B aligned)
  const int rb = s * 68 + 8 * g;   // + 32kt: two b64 reads each (8B aligned)
  float padd[4];                   // tile-3 pad indicator: n = 48+4g+r >= 51
#pragma unroll
  for (int r = 0; r < 4; ++r) padd[r] = (4 * g + r >= 3) ? 1.0f : 0.0f;

  // ---- 50-step damped fixed point ----
#pragma unroll 1
  for (int it = 0; it < 50; ++it) {
#pragma unroll
    for (int t = 0; t < 4; ++t) {
      bf16x4 hv;
#pragma unroll
      for (int r = 0; r < 4; ++r) hv[r] = (bf16)Gt[4 * t + r];
      *(bf16x4*)(lds + wb + 16 * t) = hv;
    }

    bf16x8 bfr[2];
#pragma unroll
    for (int kt = 0; kt < 2; ++kt) {
      const bf16x4 lo = *(const bf16x4*)(lds + rb + 32 * kt);
      const bf16x4 hi = *(const bf16x4*)(lds + rb + 32 * kt + 4);
      bfr[kt] = __builtin_shufflevector(lo, hi, 0, 1, 2, 3, 4, 5, 6, 7);
    }

    const f32x4 z = {};
    f32x4 acc[4];
#pragma unroll
    for (int t = 0; t < 4; ++t) acc[t] = mfma16(afr[t][0], bfr[0], z);
#pragma unroll
    for (int t = 0; t < 4; ++t) acc[t] = mfma16(afr[t][1], bfr[1], acc[t]);

    // Gt <- 0.5*(Gt + w*rcp(d)); pad rows: d = 0+1 -> rcp=1, w=0 -> Gt stays 0
#pragma unroll
    for (int t = 0; t < 3; ++t)
#pragma unroll
      for (int r = 0; r < 4; ++r) {
        const int i = 4 * t + r;
        const float rc = __builtin_amdgcn_rcpf(acc[t][r]);
        Gt[i] = 0.5f * __builtin_fmaf(wC[i], rc, Gt[i]);
      }
#pragma unroll
    for (int r = 0; r < 4; ++r) {
      const int i = 12 + r;
      const float rc = __builtin_amdgcn_rcpf(acc[3][r] + padd[r]);
      Gt[i] = 0.5f * __builtin_fmaf(wC[i], rc, Gt[i]);
    }
  }

  // ---- epilogue: S_task = sum_n psigma_pure[n] * ln(G[n]), G = Gt/w ----
  const float rA0 = __builtin_amdgcn_rcpf(A0);
  float Sp = 0.f;
#pragma unroll
  for (int t = 0; t < 4; ++t)
#pragma unroll
    for (int r = 0; r < 4; ++r) {
      const int n = 16 * t + 4 * g + r;
      if (n < 51) {
        const int i = 4 * t + r;
        const float p  = (ein ? my_sigma[(size_t)ec * 51 + n] : 0.0f) * rA0;
        const float gg = Gt[i] * __builtin_amdgcn_rcpf(wC[i]);
        Sp += p * __builtin_amdgcn_logf(gg);
      }
    }
  Sp += __shfl_xor(Sp, 16, 64);
  Sp += __shfl_xor(Sp, 32, 64);
  const float St = Sp * 0.69314718056f;
  const float So = __shfl_xor(St, 1, 64);   // partner task's sum

  if (task == 0 && g == 0 && ein) {
    const float lng_resid = A0 * (1.0f / 7.5f) * (So - St);
    const float v0  = v_comp[e];
    const float v1v = v_vt[e];
    const float q0 = A0 * (1.0f / 79.53f), q1 = A1 * (1.0f / 79.53f);
    const float r0 = v0 * (1.0f / 66.69f), r1 = v1v * (1.0f / 66.69f);
    const float xq = 0.235f * q0 + 0.765f * q1;
    const float xr = 0.235f * r0 + 0.765f * r1;
    const float theta = 0.235f * q0 * __builtin_amdgcn_rcpf(xq);
    const float phi   = 0.235f * r0 * __builtin_amdgcn_rcpf(xr);
    const float l0 = 5.0f * (r0 - q0) - (r0 - 1.0f);
    const float l1 = 5.0f * (r1 - q1) - (r1 - 1.0f);
    const float xl = 0.235f * l0 + 0.765f * l1;
    const float lng_comb = fast_log(phi * (1.0f / 0.235f))
                         + 5.0f * q0 * fast_log(theta * __builtin_amdgcn_rcpf(phi))
                         + l0 - (phi * (1.0f / 0.235f)) * xl;
    out[e] = lng_resid + lng_comb;
  }
}

extern "C" void kernel_launch(void* const* d_in, const int* in_sizes, int n_in,
                              void* d_out, int out_size, void* d_ws, size_t ws_size,
                              hipStream_t stream) {
  const float* my  = (const float*)d_in[0];
  const float* vc  = (const float*)d_in[1];
  const float* vts = (const float*)d_in[2];
  const float* vvt = (const float*)d_in[3];
  float* out = (float*)d_out;
  const int B = in_sizes[1];                    // v_compound is [B]
  const int grid = (B + 7) / 8;                 // 8 elements per 64-thread block
  cosmo_mfma_gt<<<grid, 64, 0, stream>>>(my, vc, vts, vvt, out, B);
}

// Round 9
// 115.699 us; speedup vs baseline: 1.1019x; 1.0597x over previous
//
#include <hip/hip_runtime.h>

typedef __bf16 bf16;
typedef __attribute__((ext_vector_type(4))) bf16 bf16x4;
typedef __attribute__((ext_vector_type(8))) bf16 bf16x8;
typedef __attribute__((ext_vector_type(4))) float f32x4;

namespace {

// ---- compile-time physical constants (double) ----
constexpr double csqrt(double x) {
  double s = x > 1 ? x : 1;
  for (int i = 0; i < 60; ++i) s = 0.5 * (s + x / s);
  return s;
}
constexpr double AP_D =
    ((3.667 - 1.0) / (3.667 + 0.5)) * (0.3 * (7.5 * csqrt(7.5)) / 0.0002395);
constexpr double RGAST_D = (8.3144598 / 4184.0) * 623.15;

__device__ __forceinline__ float sss_val(int i, int j) {
  // SSS[i][j] = exp(-DELTAW/(RGAS*T)); symmetric; zero outside 51x51 (pad)
  if (i > 50 || j > 50) return 0.0f;
  const float si = -0.025f + 0.001f * (float)i;
  const float sj = -0.025f + 0.001f * (float)j;
  const float acc = fmaxf(0.0f, fmaxf(si, sj) - 0.0084f);
  const float don = fminf(0.0f, fminf(si, sj) + 0.0084f);
  const float dw = (float)(AP_D * 0.5) * (si + sj) * (si + sj) + 85580.0f * acc * don;
  return expf(-dw * (float)(1.0 / RGAST_D));
}

__device__ __forceinline__ float fast_log(float x) {
  return __builtin_amdgcn_logf(x) * 0.69314718056f;   // ln via log2
}

// HW-verified gfx950 shape (guide §3; R4/R5/R8 passed with it).
__device__ __forceinline__ f32x4 mfma16(bf16x8 a, bf16x8 b, f32x4 c) {
  return __builtin_amdgcn_mfma_f32_16x16x32_bf16(a, b, c, 0, 0, 0);
}

} // namespace

// One wave = 16 solves (8 elements x {pure, mix}). ZERO cross-lane data
// movement in the hot loop: the k-dimension of S is permuted by
//   sigma(32kt + 8g + i) = 16*(2kt + (i>>2)) + 4g + (i&3)
// so the B fragment of lane (s,g) is exactly that lane's own C-layout Gt
// chunks: b_kt = concat(Gt_bf16[2kt], Gt_bf16[2kt+1]). The permutation is
// absorbed into the constant A fragments (setup only). R8 was latency-bound
// on the LDS write->read round trip (VALUBusy 60%, 780 cyc/wave-iter);
// this removes every DS op from the loop.
// State is Gt = w (.) G; update Gt' = 0.5*(Gt + w*rcp(d)).
// Pads: S rows/cols >=51 are 0; pad out-rows get d+=1, w=0 -> Gt stays 0.
__global__ __launch_bounds__(256, 4) void cosmo_mfma_perm(
    const float* __restrict__ my_sigma,   // [B,51]
    const float* __restrict__ v_comp,     // [B]
    const float* __restrict__ vt_sigma,   // [B,51,2]
    const float* __restrict__ v_vt,       // [B]
    float* __restrict__ out,              // [B]
    int B)
{
  const int lane = threadIdx.x & 63;
  const int wv   = threadIdx.x >> 6;
  const int s    = lane & 15;     // solve slot (C col / A-frag m pos)
  const int g    = lane >> 4;     // lane group 0..3
  const int e    = blockIdx.x * 32 + wv * 8 + (s >> 1);
  const int task = s & 1;         // 0 = pure, 1 = mix
  const bool ein = (e < B);
  const int  ec  = ein ? e : 0;

  // ---- rows owned by this lane in C layout: n = 16t + 4g + r ----
  float A0, A1, wC[16];
  {
    float myv[16], vtv[16];
#pragma unroll
    for (int t = 0; t < 4; ++t)
#pragma unroll
      for (int r = 0; r < 4; ++r) {
        const int n  = 16 * t + 4 * g + r;
        const bool nv = (n < 51) && ein;
        const int nc = (n < 51) ? n : 50;
        myv[4 * t + r] = nv ? my_sigma[(size_t)ec * 51 + nc] : 0.0f;
        vtv[4 * t + r] = nv ? vt_sigma[((size_t)ec * 51 + nc) * 2 + 1] : 0.0f;
      }
    float pA0 = 0.f, pA1 = 0.f;
#pragma unroll
    for (int i = 0; i < 16; ++i) { pA0 += myv[i]; pA1 += vtv[i]; }
    A0 = pA0; A0 += __shfl_xor(A0, 16, 64); A0 += __shfl_xor(A0, 32, 64);
    A1 = pA1; A1 += __shfl_xor(A1, 16, 64); A1 += __shfl_xor(A1, 32, 64);

    const float den  = task ? (0.235f * A0 + 0.765f * A1) : A0;
    const float rden = __builtin_amdgcn_rcpf(den);
#pragma unroll
    for (int i = 0; i < 16; ++i) {
      const float num = task ? (0.235f * myv[i] + 0.765f * vtv[i]) : myv[i];
      wC[i] = num * rden;     // psigma of this task; 0 on pads
    }
  }

  float Gt[16];                   // state: Gt = w * G, init G = 1
#pragma unroll
  for (int i = 0; i < 16; ++i) Gt[i] = wC[i];

  // ---- constant A fragments with permuted k:
  //      afr[tp][kt][i] = S[16tp + s][ 16*(2kt + (i>>2)) + 4g + (i&3) ] ----
  bf16x8 afr[4][2];
#pragma unroll
  for (int tp = 0; tp < 4; ++tp)
#pragma unroll
    for (int kt = 0; kt < 2; ++kt) {
      bf16x8 v;
#pragma unroll
      for (int i = 0; i < 8; ++i) {
        const int n_src = 16 * (2 * kt + (i >> 2)) + 4 * g + (i & 3);
        v[i] = (bf16)sss_val(16 * tp + s, n_src);
      }
      afr[tp][kt] = v;
    }

  float padd[4];                   // tile-3 pad indicator: n_out = 48+4g+r >= 51
#pragma unroll
  for (int r = 0; r < 4; ++r) padd[r] = (4 * g + r >= 3) ? 1.0f : 0.0f;

  // ---- 50-step damped fixed point: zero DS ops, zero shuffles ----
#pragma unroll 1
  for (int it = 0; it < 50; ++it) {
    bf16x4 hb[4];
#pragma unroll
    for (int t = 0; t < 4; ++t)
#pragma unroll
      for (int r = 0; r < 4; ++r) hb[t][r] = (bf16)Gt[4 * t + r];

    const bf16x8 b0 = __builtin_shufflevector(hb[0], hb[1], 0, 1, 2, 3, 4, 5, 6, 7);
    const bf16x8 b1 = __builtin_shufflevector(hb[2], hb[3], 0, 1, 2, 3, 4, 5, 6, 7);

    const f32x4 z = {};
    f32x4 acc[4];
#pragma unroll
    for (int tp = 0; tp < 4; ++tp) acc[tp] = mfma16(afr[tp][0], b0, z);
#pragma unroll
    for (int tp = 0; tp < 4; ++tp) acc[tp] = mfma16(afr[tp][1], b1, acc[tp]);

    // Gt <- 0.5*(Gt + w*rcp(d)); pad out-rows: d = 0+1 -> rcp=1, w=0 -> Gt=0
#pragma unroll
    for (int tp = 0; tp < 3; ++tp)
#pragma unroll
      for (int r = 0; r < 4; ++r) {
        const int i = 4 * tp + r;
        const float rc = __builtin_amdgcn_rcpf(acc[tp][r]);
        Gt[i] = 0.5f * __builtin_fmaf(wC[i], rc, Gt[i]);
      }
#pragma unroll
    for (int r = 0; r < 4; ++r) {
      const int i = 12 + r;
      const float rc = __builtin_amdgcn_rcpf(acc[3][r] + padd[r]);
      Gt[i] = 0.5f * __builtin_fmaf(wC[i], rc, Gt[i]);
    }
  }

  // ---- epilogue: S_task = sum_n psigma_pure[n] * ln(G[n]), G = Gt/w ----
  const float rA0 = __builtin_amdgcn_rcpf(A0);
  float Sp = 0.f;
#pragma unroll
  for (int t = 0; t < 4; ++t)
#pragma unroll
    for (int r = 0; r < 4; ++r) {
      const int n = 16 * t + 4 * g + r;
      if (n < 51) {
        const int i = 4 * t + r;
        const float p  = (ein ? my_sigma[(size_t)ec * 51 + n] : 0.0f) * rA0;
        // guard wC==0 (possible exact-0 input): p==0 there, force ln arg -> 1
        const float gg = (wC[i] != 0.0f)
                           ? Gt[i] * __builtin_amdgcn_rcpf(wC[i]) : 1.0f;
        Sp += p * __builtin_amdgcn_logf(gg);
      }
    }
  Sp += __shfl_xor(Sp, 16, 64);
  Sp += __shfl_xor(Sp, 32, 64);
  const float St = Sp * 0.69314718056f;
  const float So = __shfl_xor(St, 1, 64);   // partner task's sum

  if (task == 0 && g == 0 && ein) {
    const float lng_resid = A0 * (1.0f / 7.5f) * (So - St);
    const float v0  = v_comp[e];
    const float v1v = v_vt[e];
    const float q0 = A0 * (1.0f / 79.53f), q1 = A1 * (1.0f / 79.53f);
    const float r0 = v0 * (1.0f / 66.69f), r1 = v1v * (1.0f / 66.69f);
    const float xq = 0.235f * q0 + 0.765f * q1;
    const float xr = 0.235f * r0 + 0.765f * r1;
    const float theta = 0.235f * q0 * __builtin_amdgcn_rcpf(xq);
    const float phi   = 0.235f * r0 * __builtin_amdgcn_rcpf(xr);
    const float l0 = 5.0f * (r0 - q0) - (r0 - 1.0f);
    const float l1 = 5.0f * (r1 - q1) - (r1 - 1.0f);
    const float xl = 0.235f * l0 + 0.765f * l1;
    const float lng_comb = fast_log(phi * (1.0f / 0.235f))
                         + 5.0f * q0 * fast_log(theta * __builtin_amdgcn_rcpf(phi))
                         + l0 - (phi * (1.0f / 0.235f)) * xl;
    out[e] = lng_resid + lng_comb;
  }
}

extern "C" void kernel_launch(void* const* d_in, const int* in_sizes, int n_in,
                              void* d_out, int out_size, void* d_ws, size_t ws_size,
                              hipStream_t stream) {
  const float* my  = (const float*)d_in[0];
  const float* vc  = (const float*)d_in[1];
  const float* vts = (const float*)d_in[2];
  const float* vvt = (const float*)d_in[3];
  float* out = (float*)d_out;
  const int B = in_sizes[1];                    // v_compound is [B]
  const int grid = (B + 31) / 32;               // 32 elements per 256-thread block
  cosmo_mfma_perm<<<grid, 256, 0, stream>>>(my, vc, vts, vvt, out, B);
}